// Round 5
// baseline (433.600 us; speedup 1.0000x reference)
//
#include <hip/hip_runtime.h>
#include <cstdint>

// Problem constants
#define TOKENS 16384      // BATCH(8) * SEQ(2048)
#define DMODEL 1024
#define NHEADS 16
#define HDIM   64

typedef __bf16  bf16x8 __attribute__((ext_vector_type(8)));
typedef ushort  u16x8  __attribute__((ext_vector_type(8)));
typedef ushort  u16x4  __attribute__((ext_vector_type(4)));
typedef short   s16x4  __attribute__((ext_vector_type(4)));
typedef float   f32x4  __attribute__((ext_vector_type(4)));

#if defined(__has_builtin)
#if __has_builtin(__builtin_amdgcn_mfma_f32_16x16x16bf16_1k)
#define HAVE_MFMA_K16 1
#endif
#endif

// fp32 -> bf16 (round-half-up; inputs are well-scaled normals, no overflow risk)
__device__ __forceinline__ ushort f2bf(float f) {
    union { float f; unsigned int i; } v; v.f = f;
    return (ushort)((v.i + 0x8000u) >> 16);
}
__device__ __forceinline__ f32x4 mfma16(bf16x8 a, bf16x8 b, f32x4 c) {
    return __builtin_amdgcn_mfma_f32_16x16x32_bf16(a, b, c, 0, 0, 0);
}
// async global->LDS direct copy, 16B per lane. LDS dest must be linear in lane.
__device__ __forceinline__ void gload_lds16(const void* g, void* l) {
    __builtin_amdgcn_global_load_lds(
        (const __attribute__((address_space(1))) unsigned int*)(uintptr_t)g,
        (__attribute__((address_space(3))) unsigned int*)(uintptr_t)l,
        16, 0, 0);
}
union BU { u16x8 u; bf16x8 b; };

// ---------------------------------------------------------------------------
// Elementwise fp32 -> bf16 convert, up to 4 tensors via blockIdx.y.
// ---------------------------------------------------------------------------
struct CvtArgs {
    const float* src[4];
    ushort*      dst[4];
};

__global__ __launch_bounds__(256) void cvt_f32_bf16(CvtArgs a)
{
    const float* __restrict__ s = a.src[blockIdx.y];
    ushort*      __restrict__ d = a.dst[blockIdx.y];
    const long i = ((long)blockIdx.x * 256 + threadIdx.x) * 8;
    const f32x4 v0 = *(const f32x4*)(s + i);
    const f32x4 v1 = *(const f32x4*)(s + i + 4);
    u16x8 p;
    #pragma unroll
    for (int j = 0; j < 4; j++) {
        p[j]     = f2bf(v0[j]);
        p[4 + j] = f2bf(v1[j]);
    }
    *(u16x8*)(d + i) = p;
}

// ---------------------------------------------------------------------------
// NT GEMM, deep pipeline (T1+T2+T3+T4+T5) — unchanged from R4 (verified).
// 256x256 tile, BK=32, 512 threads = 8 waves (2M x 4N), 4-slot LDS ring,
// counted vmcnt(8) per K-tile.
// ---------------------------------------------------------------------------
#define BM2 256
#define BN2 256
#define BK2 32

struct GemmArgs {
    const ushort* A[3];
    const ushort* W[3];
    const float*  Bi[3];
    void*         C[3];
};

#define G256_READ_B(slot)                                                     \
    { _Pragma("unroll")                                                       \
      for (int n = 0; n < 4; ++n)                                             \
          bf[n] = *(const bf16x8*)&Bs[slot][(wn * 64 + n * 16 + fr) * BK2 + fks]; }

#define G256_READ_A(slot, mh)                                                 \
    { _Pragma("unroll")                                                       \
      for (int m = 0; m < 4; ++m)                                             \
          af[m] = *(const bf16x8*)&As[slot][(wm * 128 + (mh) * 64 + m * 16 + fr) * BK2 + fks]; }

#define G256_MFMA(mh)                                                         \
    { __builtin_amdgcn_s_setprio(1);                                          \
      _Pragma("unroll")                                                       \
      for (int m = 0; m < 4; ++m)                                             \
          _Pragma("unroll")                                                   \
          for (int n = 0; n < 4; ++n)                                         \
              acc[(mh) * 4 + m][n] = mfma16(af[m], bf[n], acc[(mh) * 4 + m][n]); \
      __builtin_amdgcn_s_setprio(0); }

template<int BF16OUT>
__global__ __launch_bounds__(512) void gemm256(GemmArgs args, int N, int K)
{
    __shared__ __align__(16) ushort As[4][BM2 * BK2];   // 4 x 16 KB
    __shared__ __align__(16) ushort Bs[4][BN2 * BK2];   // 4 x 16 KB

    // bijective XCD-chunked swizzle (m204 variant, any nwg)
    const int gx = gridDim.x, gy = gridDim.y;
    const int lin = (blockIdx.z * gy + blockIdx.y) * gx + blockIdx.x;
    const int nwg = gx * gy * gridDim.z;
    const int q = nwg >> 3, r = nwg & 7;
    const int xcd = lin & 7, loc = lin >> 3;
    const int swz = (xcd < r ? xcd * (q + 1) : r * (q + 1) + (xcd - r) * q) + loc;
    const int bz  = swz / (gx * gy);
    const int rem = swz - bz * gx * gy;
    const int by  = rem / gx;
    const int bx  = rem - by * gx;

    const ushort* __restrict__ A  = args.A[bz];
    const ushort* __restrict__ W  = args.W[bz];
    const float*  __restrict__ Bi = args.Bi[bz];

    const int tid  = threadIdx.x;
    const int wave = tid >> 6;
    const int lane = tid & 63;
    const int wm = wave >> 2;          // 0..1 row-wave
    const int wn = wave & 3;           // 0..3 col-wave
    const long rowBase = (long)by * BM2;
    const long colBase = (long)bx * BN2;

    const int gA0 = tid, gA1 = tid + 512;
    const long aOff0 = (long)(gA0 >> 2) * K + (((gA0 & 3) ^ ((gA0 >> 3) & 3)) * 8);
    const long aOff1 = (long)(gA1 >> 2) * K + (((gA1 & 3) ^ ((gA1 >> 3) & 3)) * 8);
    const ushort* Abase = A + rowBase * K;
    const ushort* Wbase = W + colBase * K;

    const int fr  = lane & 15;
    const int fks = (((lane >> 4) ^ ((fr >> 1) & 3)) * 8);

    f32x4 acc[8][4];
    #pragma unroll
    for (int m = 0; m < 8; ++m)
        #pragma unroll
        for (int n = 0; n < 4; ++n)
            acc[m][n] = (f32x4){0.f, 0.f, 0.f, 0.f};

    auto stageA = [&](int slot, int kt) {
        gload_lds16(Abase + aOff0 + (long)kt * BK2, &As[slot][gA0 * 8]);
        gload_lds16(Abase + aOff1 + (long)kt * BK2, &As[slot][gA1 * 8]);
    };
    auto stageB = [&](int slot, int kt) {
        gload_lds16(Wbase + aOff0 + (long)kt * BK2, &Bs[slot][gA0 * 8]);
        gload_lds16(Wbase + aOff1 + (long)kt * BK2, &Bs[slot][gA1 * 8]);
    };

    const int nt = K / BK2;

    stageA(0, 0); stageB(0, 0);
    stageA(1, 1); stageB(1, 1);
    stageA(2, 2); stageB(2, 2);
    asm volatile("s_waitcnt vmcnt(8)" ::: "memory");
    __builtin_amdgcn_s_barrier();

    bf16x8 af[4], bf[4];

    for (int X = 0; X < nt - 3; ++X) {
        const int slot = X & 3, st = (X + 3) & 3;
        G256_READ_B(slot);
        G256_READ_A(slot, 0);
        stageA(st, X + 3);
        G256_MFMA(0);
        __builtin_amdgcn_s_barrier();
        G256_READ_A(slot, 1);
        stageB(st, X + 3);
        G256_MFMA(1);
        asm volatile("s_waitcnt vmcnt(8)" ::: "memory");
        __builtin_amdgcn_s_barrier();
    }
    {
        const int slot = (nt - 3) & 3;
        G256_READ_B(slot);
        G256_READ_A(slot, 0);
        G256_MFMA(0);
        __builtin_amdgcn_s_barrier();
        G256_READ_A(slot, 1);
        G256_MFMA(1);
        asm volatile("s_waitcnt vmcnt(4)" ::: "memory");
        __builtin_amdgcn_s_barrier();
    }
    {
        const int slot = (nt - 2) & 3;
        G256_READ_B(slot);
        G256_READ_A(slot, 0);
        G256_MFMA(0);
        __builtin_amdgcn_s_barrier();
        G256_READ_A(slot, 1);
        G256_MFMA(1);
        asm volatile("s_waitcnt vmcnt(0)" ::: "memory");
        __builtin_amdgcn_s_barrier();
    }
    {
        const int slot = (nt - 1) & 3;
        G256_READ_B(slot);
        G256_READ_A(slot, 0);
        G256_MFMA(0);
        __builtin_amdgcn_s_barrier();
        G256_READ_A(slot, 1);
        G256_MFMA(1);
    }

    const int qd = lane >> 4;
    #pragma unroll
    for (int n = 0; n < 4; ++n) {
        const long col = colBase + wn * 64 + n * 16 + fr;
        const float bv = Bi[col];
        #pragma unroll
        for (int m = 0; m < 8; ++m) {
            const long r0 = rowBase + wm * 128 + m * 16 + qd * 4;
            #pragma unroll
            for (int r2 = 0; r2 < 4; ++r2) {
                const float val = acc[m][n][r2] + bv;
                if (BF16OUT)
                    ((ushort*)args.C[bz])[(r0 + r2) * (long)N + col] = f2bf(val);
                else
                    ((float*)args.C[bz])[(r0 + r2) * (long)N + col] = val;
            }
        }
    }
}

// ---------------------------------------------------------------------------
// Fused per-token attention (16x16 head-gram) + LayerNorm — restructured.
// One wave per token; 4 tokens per 256-thread block; ZERO barriers (all state
// wave-local).
//   E^T = mfma(K,Q): lane (fr,hi) holds E[h=fr][g=hi*4+r] -> softmax over g is
//   4 local ops + 2 shfls; P lands exactly in the 16x16x16 A-fragment layout
//   (no LDS bounce for P).
//   PV: mfma_f32_16x16x16_bf16, B-frag = 16 scalar V reads, conflict-free via
//   source-side XOR swizzle on the V staging (linear LDS dest, rule #21):
//   granule(g, d8) stored at g*8 + (d8 ^ (((g>>2)&3)<<1)).
//   Output: per-wave LDS transpose (stride 68, conflict-free) -> each lane
//   owns 16 contiguous token elems -> vectorized ln_g/ln_b loads + coalesced
//   u16x8 stores.
// ---------------------------------------------------------------------------
#define PMS 40    // fallback Pm row stride (u16)

__global__ __launch_bounds__(256) void attn_ln_mfma(
    const ushort* __restrict__ Qp, const ushort* __restrict__ Kp,
    const ushort* __restrict__ Vp,
    const float* __restrict__ lng, const float* __restrict__ lnb,
    ushort* __restrict__ O)
{
#if HAVE_MFMA_K16
    __shared__ __align__(16) ushort Vs[4][1024];       // per-wave V, swizzled
#else
    __shared__ __align__(16) ushort Vs[4][2048];       // + slack for K32 reads
    __shared__ __align__(16) ushort Pm[4][16 * PMS];
#endif
    __shared__ __align__(16) float Os[4][16 * 68];     // per-wave out transpose

    const int tid  = threadIdx.x;
    const int w    = tid >> 6;
    const int lane = tid & 63;
    const long tok  = (long)blockIdx.x * 4 + w;
    const long base = tok * DMODEL;

    // stage V: linear LDS dest, pre-swizzled global source.
    // dest granule i holds global (g = i>>3, d8 = (i&7) ^ (((i>>5)&3)<<1))
    {
        const int i0 = lane, i1 = lane + 64;
        const int g0 = i0 >> 3, d80 = (i0 & 7) ^ (((i0 >> 5) & 3) << 1);
        const int g1 = i1 >> 3, d81 = (i1 & 7) ^ (((i1 >> 5) & 3) << 1);
        gload_lds16(Vp + base + g0 * 64 + d80 * 8, &Vs[w][i0 * 8]);
        gload_lds16(Vp + base + g1 * 64 + d81 * 8, &Vs[w][i1 * 8]);
    }

    const int fr = lane & 15;
    const int hi = lane >> 4;
    const int fs = hi * 8;

    // QK^T fragments directly from global (token row is 2KB, cache-resident)
    const bf16x8 aq0 = *(const bf16x8*)(Qp + base + fr * 64 + fs);
    const bf16x8 aq1 = *(const bf16x8*)(Qp + base + fr * 64 + fs + 32);
    const bf16x8 bk0 = *(const bf16x8*)(Kp + base + fr * 64 + fs);
    const bf16x8 bk1 = *(const bf16x8*)(Kp + base + fr * 64 + fs + 32);

    // swapped operands: E^T[g][h]; lane (fr,hi) holds E[h=fr][g=hi*4+r]
    f32x4 e = (f32x4){0.f, 0.f, 0.f, 0.f};
    e = mfma16(bk0, aq0, e);
    e = mfma16(bk1, aq1, e);

    // softmax over g: 4-local + shfl_xor(16,32)
    float x[4];
    #pragma unroll
    for (int r = 0; r < 4; ++r) x[r] = e[r] * 0.03125f;   // 1/sqrt(1024)
    float mx = fmaxf(fmaxf(x[0], x[1]), fmaxf(x[2], x[3]));
    mx = fmaxf(mx, __shfl_xor(mx, 16, 64));
    mx = fmaxf(mx, __shfl_xor(mx, 32, 64));
    float ex[4], sm;
    #pragma unroll
    for (int r = 0; r < 4; ++r) ex[r] = __expf(x[r] - mx);
    sm = (ex[0] + ex[1]) + (ex[2] + ex[3]);
    sm += __shfl_xor(sm, 16, 64);
    sm += __shfl_xor(sm, 32, 64);
    const float inv = 1.0f / sm;
    float p[4];
    #pragma unroll
    for (int r = 0; r < 4; ++r) p[r] = ex[r] * inv;

    f32x4 o[4];

#if HAVE_MFMA_K16
    // P is already the 16x16x16 A-fragment: A[h=fr][k=g=hi*4+j] = p[j]
    s16x4 pa;
    #pragma unroll
    for (int r = 0; r < 4; ++r) pa[r] = (short)f2bf(p[r]);

    asm volatile("s_waitcnt vmcnt(0)" ::: "memory");   // V staged (wave-local)

    #pragma unroll
    for (int dblk = 0; dblk < 4; ++dblk) {
        s16x4 bv;
        #pragma unroll
        for (int j = 0; j < 4; ++j) {
            const int g = hi * 4 + j;
            const int d = dblk * 16 + fr;
            const int ad = g * 64 + (((d >> 3) ^ (((g >> 2) & 3) << 1)) * 8) + (d & 7);
            bv[j] = (short)Vs[w][ad];
        }
        o[dblk] = __builtin_amdgcn_mfma_f32_16x16x16bf16_1k(
            pa, bv, (f32x4){0.f, 0.f, 0.f, 0.f}, 0, 0, 0);
    }
#else
    // fallback: bounce P through LDS, K=32 MFMA with zero-padded k>=16
    *(u16x4*)&Pm[w][fr * PMS + 16 + hi * 4] = (u16x4){0, 0, 0, 0};
    #pragma unroll
    for (int r = 0; r < 4; ++r)
        Pm[w][fr * PMS + hi * 4 + r] = f2bf(p[r]);
    asm volatile("s_waitcnt vmcnt(0)" ::: "memory");
    const bf16x8 pa8 = *(const bf16x8*)&Pm[w][fr * PMS + fs];
    #pragma unroll
    for (int dblk = 0; dblk < 4; ++dblk) {
        BU bu;
        #pragma unroll
        for (int j = 0; j < 8; ++j) {
            const int g = fs + j;                     // g>=16: garbage * P=0
            const int d = dblk * 16 + fr;
            const int ad = g * 64 + (((d >> 3) ^ (((g >> 2) & 3) << 1)) * 8) + (d & 7);
            bu.u[j] = Vs[w][ad];
        }
        o[dblk] = mfma16(pa8, bu.b, (f32x4){0.f, 0.f, 0.f, 0.f});
    }
#endif
    // lane holds out[h=hi*4+r][d=dblk*16+fr]

    // LayerNorm stats over 1024: 16 regs/lane x 64 lanes
    float s1 = 0.f, s2 = 0.f;
    #pragma unroll
    for (int dblk = 0; dblk < 4; ++dblk)
        #pragma unroll
        for (int r = 0; r < 4; ++r) { const float v = o[dblk][r]; s1 += v; s2 += v * v; }
    #pragma unroll
    for (int m = 1; m < 64; m <<= 1) {
        s1 += __shfl_xor(s1, m, 64);
        s2 += __shfl_xor(s2, m, 64);
    }
    const float mu   = s1 * (1.f / DMODEL);
    const float var  = s2 * (1.f / DMODEL) - mu * mu;
    const float rstd = rsqrtf(var + 1e-5f);

    // transpose via per-wave LDS (stride 68: conflict-free both directions)
    #pragma unroll
    for (int dblk = 0; dblk < 4; ++dblk)
        #pragma unroll
        for (int r = 0; r < 4; ++r)
            Os[w][(hi * 4 + r) * 68 + dblk * 16 + fr] = (o[dblk][r] - mu) * rstd;

    // lane owns token elems lane*16 .. lane*16+15 (h=lane>>2, d=(lane&3)*16+j)
    u16x8 s0, s1v;
    #pragma unroll
    for (int c = 0; c < 4; ++c) {
        const f32x4 yv = *(const f32x4*)&Os[w][(lane >> 2) * 68 + (lane & 3) * 16 + c * 4];
        const f32x4 lg = *(const f32x4*)(lng + lane * 16 + c * 4);
        const f32x4 lb = *(const f32x4*)(lnb + lane * 16 + c * 4);
        #pragma unroll
        for (int j = 0; j < 4; ++j) {
            const ushort hv = f2bf(yv[j] * lg[j] + lb[j]);
            if (c < 2) s0[c * 4 + j] = hv; else s1v[(c - 2) * 4 + j] = hv;
        }
    }
    *(u16x8*)(O + base + lane * 16)     = s0;
    *(u16x8*)(O + base + lane * 16 + 8) = s1v;
}

// ---------------------------------------------------------------------------
// launch — ws-size-adaptive chunked pipeline (unchanged).
// ---------------------------------------------------------------------------
extern "C" void kernel_launch(void* const* d_in, const int* in_sizes, int n_in,
                              void* d_out, int out_size, void* d_ws, size_t ws_size,
                              hipStream_t stream)
{
    const float* query = (const float*)d_in[0];
    const float* key   = (const float*)d_in[1];
    const float* value = (const float*)d_in[2];
    const float* Wq = (const float*)d_in[3];
    const float* bq = (const float*)d_in[4];
    const float* Wk = (const float*)d_in[5];
    const float* bk = (const float*)d_in[6];
    const float* Wv = (const float*)d_in[7];
    const float* bv = (const float*)d_in[8];
    const float* lng = (const float*)d_in[9];
    const float* lnb = (const float*)d_in[10];
    const float* Wo = (const float*)d_in[11];
    const float* bo = (const float*)d_in[12];
    float* out = (float*)d_out;

    const long WELEMS = (long)DMODEL * DMODEL;       // 1Mi elems per weight

    ushort* wq_b = (ushort*)d_ws;
    ushort* wk_b = wq_b + WELEMS;
    ushort* wv_b = wk_b + WELEMS;
    ushort* wo_b = wv_b + WELEMS;
    ushort* cbuf = wo_b + WELEMS;                    // per-chunk region

    // bytes needed: 8MB weights + CM*1024*(5 bf16 bufs * 2B) = 8MB + CM*10240
    // NC capped at 64 so CM stays a multiple of 256 (BM2 tile).
    int NC = 1;
    while (NC < 64 &&
           (size_t)(8 * WELEMS) + (size_t)(TOKENS / NC) * DMODEL * 10 > ws_size)
        NC <<= 1;
    const int CM = TOKENS / NC;                 // tokens per chunk (mult of 256)
    const size_t CE = (size_t)CM * DMODEL;      // elems per chunk buffer

    ushort* qb = cbuf;            // query bf16; later reused for attn bf16 out
    ushort* kb = qb + CE;
    ushort* vb = kb + CE;
    ushort* qp = vb + CE;         // bf16 Q-projection (attn input)
    ushort* vp = qp + CE;         // bf16 V-projection (attn input)

    // 0) convert weights fp32 -> bf16 (once)
    {
        CvtArgs cw;
        cw.src[0] = Wq; cw.src[1] = Wk; cw.src[2] = Wv; cw.src[3] = Wo;
        cw.dst[0] = wq_b; cw.dst[1] = wk_b; cw.dst[2] = wv_b; cw.dst[3] = wo_b;
        cvt_f32_bf16<<<dim3((unsigned)(WELEMS / 2048), 4), 256, 0, stream>>>(cw);
    }

    for (int c = 0; c < NC; ++c) {
        const size_t off = (size_t)c * CE;
        ushort* kp = (ushort*)(out + off);      // bf16 scratch in d_out chunk

        // 1) convert this chunk's query/key/value fp32 -> bf16
        {
            CvtArgs ci;
            ci.src[0] = query + off; ci.src[1] = key + off; ci.src[2] = value + off;
            ci.src[3] = query;  // unused (z<3)
            ci.dst[0] = qb; ci.dst[1] = kb; ci.dst[2] = vb; ci.dst[3] = qb;
            cvt_f32_bf16<<<dim3((unsigned)(CE / 2048), 3), 256, 0, stream>>>(ci);
        }

        // 2) fused QKV projections, bf16 outputs (z picks q/k/v)
        GemmArgs g1;
        g1.A[0] = qb;    g1.A[1] = kb;   g1.A[2] = vb;
        g1.W[0] = wq_b;  g1.W[1] = wk_b; g1.W[2] = wv_b;
        g1.Bi[0] = bq;   g1.Bi[1] = bk;  g1.Bi[2] = bv;
        g1.C[0] = qp;    g1.C[1] = kp;   g1.C[2] = vp;
        gemm256<1><<<dim3(DMODEL / BN2, CM / BM2, 3), 512, 0, stream>>>(
            g1, DMODEL, DMODEL);

        // 3) per-token attention + LayerNorm -> bf16 into qb (dead after GEMM1)
        attn_ln_mfma<<<CM / 4, 256, 0, stream>>>(qp, kp, vp, lng, lnb, qb);

        // 4) output projection -> d_out chunk fp32 (overwrites kp scratch)
        GemmArgs g2;
        g2.A[0] = g2.A[1] = g2.A[2] = qb;
        g2.W[0] = g2.W[1] = g2.W[2] = wo_b;
        g2.Bi[0] = g2.Bi[1] = g2.Bi[2] = bo;
        g2.C[0] = g2.C[1] = g2.C[2] = out + off;
        gemm256<0><<<dim3(DMODEL / BN2, CM / BM2, 1), 512, 0, stream>>>(
            g2, DMODEL, DMODEL);
    }
}

// Round 6
// 393.510 us; speedup vs baseline: 1.1019x; 1.1019x over previous
//
#include <hip/hip_runtime.h>
#include <cstdint>

// Problem constants
#define TOKENS 16384      // BATCH(8) * SEQ(2048)
#define DMODEL 1024
#define NHEADS 16
#define HDIM   64

typedef __bf16  bf16x8 __attribute__((ext_vector_type(8)));
typedef ushort  u16x8  __attribute__((ext_vector_type(8)));
typedef ushort  u16x4  __attribute__((ext_vector_type(4)));
typedef short   s16x4  __attribute__((ext_vector_type(4)));
typedef float   f32x4  __attribute__((ext_vector_type(4)));

#if defined(__has_builtin)
#if __has_builtin(__builtin_amdgcn_mfma_f32_16x16x16bf16_1k)
#define HAVE_MFMA_K16 1
#endif
#endif

// fp32 -> bf16 (round-half-up; inputs are well-scaled normals, no overflow risk)
__device__ __forceinline__ ushort f2bf(float f) {
    union { float f; unsigned int i; } v; v.f = f;
    return (ushort)((v.i + 0x8000u) >> 16);
}
__device__ __forceinline__ f32x4 mfma16(bf16x8 a, bf16x8 b, f32x4 c) {
    return __builtin_amdgcn_mfma_f32_16x16x32_bf16(a, b, c, 0, 0, 0);
}
// async global->LDS direct copy, 16B per lane. LDS dest must be linear in lane.
__device__ __forceinline__ void gload_lds16(const void* g, void* l) {
    __builtin_amdgcn_global_load_lds(
        (const __attribute__((address_space(1))) unsigned int*)(uintptr_t)g,
        (__attribute__((address_space(3))) unsigned int*)(uintptr_t)l,
        16, 0, 0);
}
union BU { u16x8 u; bf16x8 b; };

// ---------------------------------------------------------------------------
// Elementwise fp32 -> bf16 convert (weights only now), 4 tensors via blockIdx.y.
// ---------------------------------------------------------------------------
struct CvtArgs {
    const float* src[4];
    ushort*      dst[4];
};

__global__ __launch_bounds__(256) void cvt_f32_bf16(CvtArgs a)
{
    const float* __restrict__ s = a.src[blockIdx.y];
    ushort*      __restrict__ d = a.dst[blockIdx.y];
    const long i = ((long)blockIdx.x * 256 + threadIdx.x) * 8;
    const f32x4 v0 = *(const f32x4*)(s + i);
    const f32x4 v1 = *(const f32x4*)(s + i + 4);
    u16x8 p;
    #pragma unroll
    for (int j = 0; j < 4; j++) {
        p[j]     = f2bf(v0[j]);
        p[4 + j] = f2bf(v1[j]);
    }
    *(u16x8*)(d + i) = p;
}

// ---------------------------------------------------------------------------
// NT GEMM, deep pipeline (T1+T2+T3+T4+T5).  C[m,n] = sum_k A[m,k]*W[n,k]+bias.
// 256x256 tile, BK=32, 512 threads = 8 waves (2M x 4N), 4-slot LDS ring.
// AFP32=0: A bf16 via global_load_lds (R4-verified schedule, vmcnt 8/4/0).
// AFP32=1: A fp32 reg-staged (issue loads for tile X+2 in phase E; convert +
//   swizzled ds_write of tile X+1 in phase O after the counted vmcnt(8)).
//   FIFO proof (steady): retire B(X+1) <=> allow B(X+2)2 + Areg(X+2)4 +
//   B(X+3)2 = 8 outstanding — invariant under any legal reorder of load
//   issues within the asm-fenced windows. Tails: 6 then 0.
// W always bf16 via global_load_lds with T2 source-side swizzle; LDS granule
// (row r, slot s) holds k-slice s ^ ((r>>1)&3); read uses the same XOR.
// ---------------------------------------------------------------------------
#define BM2 256
#define BN2 256
#define BK2 32

struct GemmArgs {
    const void*   A[3];     // fp32 (AFP32=1) or bf16 (AFP32=0)
    const ushort* W[3];
    const float*  Bi[3];
    void*         C[3];
};

#define G256_READ_B(slot)                                                     \
    { _Pragma("unroll")                                                       \
      for (int n = 0; n < 4; ++n)                                             \
          bf[n] = *(const bf16x8*)&Bs[slot][(wn * 64 + n * 16 + fr) * BK2 + fks]; }

#define G256_READ_A(slot, mh)                                                 \
    { _Pragma("unroll")                                                       \
      for (int m = 0; m < 4; ++m)                                             \
          af[m] = *(const bf16x8*)&As[slot][(wm * 128 + (mh) * 64 + m * 16 + fr) * BK2 + fks]; }

#define G256_MFMA(mh)                                                         \
    { __builtin_amdgcn_s_setprio(1);                                          \
      _Pragma("unroll")                                                       \
      for (int m = 0; m < 4; ++m)                                             \
          _Pragma("unroll")                                                   \
          for (int n = 0; n < 4; ++n)                                         \
              acc[(mh) * 4 + m][n] = mfma16(af[m], bf[n], acc[(mh) * 4 + m][n]); \
      __builtin_amdgcn_s_setprio(0); }

// reg-staged A: issue 4x dwordx4 fp32 into named regs (prefix P -> P0..P3)
#define ISSUE_A(P, kt)                                                        \
    {   const float* ap_ = Af + (kt);                                         \
        P##0 = *(const f32x4*)(ap_ + aF0);                                    \
        P##1 = *(const f32x4*)(ap_ + aF0 + 4);                                \
        P##2 = *(const f32x4*)(ap_ + aF1);                                    \
        P##3 = *(const f32x4*)(ap_ + aF1 + 4);                                \
    }
// convert + swizzled ds_write_b128 x2 into slot
#define WRITE_A(slot, P)                                                      \
    {   u16x8 p0_, p1_;                                                       \
        _Pragma("unroll")                                                     \
        for (int j_ = 0; j_ < 4; ++j_) {                                      \
            p0_[j_] = f2bf(P##0[j_]); p0_[4 + j_] = f2bf(P##1[j_]);           \
            p1_[j_] = f2bf(P##2[j_]); p1_[4 + j_] = f2bf(P##3[j_]);           \
        }                                                                     \
        *(u16x8*)&As[slot][wg0 * 8] = p0_;                                    \
        *(u16x8*)&As[slot][wg1 * 8] = p1_;                                    \
    }

#define STEADY_TILE(XV, IB, WB)                                               \
    {   const int slot_ = (XV) & 3, st_ = ((XV) + 3) & 3;                     \
        G256_READ_B(slot_);                                                   \
        G256_READ_A(slot_, 0);                                                \
        ISSUE_A(IB, ((XV) + 2) * BK2);                                        \
        G256_MFMA(0);                                                         \
        __builtin_amdgcn_s_barrier();                                         \
        G256_READ_A(slot_, 1);                                                \
        stageB(st_, (XV) + 3);                                                \
        asm volatile("s_waitcnt vmcnt(8)" ::: "memory");                      \
        WRITE_A(((XV) + 1) & 3, WB);                                          \
        G256_MFMA(1);                                                         \
        asm volatile("s_waitcnt lgkmcnt(0)" ::: "memory");                    \
        __builtin_amdgcn_s_barrier();                                         \
    }

template<int BF16OUT, int AFP32>
__global__ __launch_bounds__(512) void gemm256(GemmArgs args, int N, int K)
{
    __shared__ __align__(16) ushort As[4][BM2 * BK2];   // 4 x 16 KB
    __shared__ __align__(16) ushort Bs[4][BN2 * BK2];   // 4 x 16 KB

    // bijective XCD-chunked swizzle (m204 variant, any nwg)
    const int gx = gridDim.x, gy = gridDim.y;
    const int lin = (blockIdx.z * gy + blockIdx.y) * gx + blockIdx.x;
    const int nwg = gx * gy * gridDim.z;
    const int q = nwg >> 3, r = nwg & 7;
    const int xcd = lin & 7, loc = lin >> 3;
    const int swz = (xcd < r ? xcd * (q + 1) : r * (q + 1) + (xcd - r) * q) + loc;
    const int bz  = swz / (gx * gy);
    const int rem = swz - bz * gx * gy;
    const int by  = rem / gx;
    const int bx  = rem - by * gx;

    const ushort* __restrict__ W  = args.W[bz];
    const float*  __restrict__ Bi = args.Bi[bz];

    const int tid  = threadIdx.x;
    const int wave = tid >> 6;
    const int lane = tid & 63;
    const int wm = wave >> 2;          // 0..1 row-wave
    const int wn = wave & 3;           // 0..3 col-wave
    const long rowBase = (long)by * BM2;
    const long colBase = (long)bx * BN2;

    // staging granules (DMA paths): granule g = tid, tid+512; LDS dest g*16B
    // linear; global source row g>>2, swizzled k-slice (g&3)^((g>>3)&3).
    const int gA0 = tid, gA1 = tid + 512;
    const long sOff0 = (long)(gA0 >> 2) * K + (((gA0 & 3) ^ ((gA0 >> 3) & 3)) * 8);
    const long sOff1 = (long)(gA1 >> 2) * K + (((gA1 & 3) ^ ((gA1 >> 3) & 3)) * 8);
    const ushort* Wbase = W + colBase * K;

    // reg-staged A (AFP32=1): natural global k-slice, swizzled LDS granule
    const int arow0 = gA0 >> 2, arow1 = gA1 >> 2;
    const long aF0 = (long)arow0 * K + (gA0 & 3) * 8;
    const long aF1 = (long)arow1 * K + (gA1 & 3) * 8;
    const int wg0 = arow0 * 4 + ((gA0 & 3) ^ ((arow0 >> 1) & 3));
    const int wg1 = arow1 * 4 + ((gA1 & 3) ^ ((arow1 >> 1) & 3));
    const float* Af = (const float*)args.A[bz] + rowBase * K;

    // fragment addressing: swizzled k-slot, same for all 16-row sub-tiles
    const int fr  = lane & 15;
    const int fks = (((lane >> 4) ^ ((fr >> 1) & 3)) * 8);

    f32x4 acc[8][4];
    #pragma unroll
    for (int m = 0; m < 8; ++m)
        #pragma unroll
        for (int n = 0; n < 4; ++n)
            acc[m][n] = (f32x4){0.f, 0.f, 0.f, 0.f};

    auto stageB = [&](int slot, int kt) {
        gload_lds16(Wbase + sOff0 + (long)kt * BK2, &Bs[slot][gA0 * 8]);
        gload_lds16(Wbase + sOff1 + (long)kt * BK2, &Bs[slot][gA1 * 8]);
    };

    const int nt = K / BK2;            // 32 for K=1024; assumes nt even, >= 8
    bf16x8 af[4], bf[4];

    if constexpr (AFP32) {
        f32x4 arA0, arA1, arA2, arA3, arB0, arB1, arB2, arB3;

        // prologue: A(0)->arA, A(1)->arB, B(0..2) DMA; write A(0); tile0 ready
        ISSUE_A(arA, 0);
        ISSUE_A(arB, BK2);
        stageB(0, 0); stageB(1, 1); stageB(2, 2);
        asm volatile("s_waitcnt vmcnt(10)" ::: "memory");   // A(0) arrived
        WRITE_A(0, arA);
        asm volatile("s_waitcnt vmcnt(4)" ::: "memory");    // B(0) landed
        asm volatile("s_waitcnt lgkmcnt(0)" ::: "memory");
        __builtin_amdgcn_s_barrier();

        // steady tiles X = 0 .. nt-4 (nt-3 of them; nt even -> count is odd:
        // unroll-by-2 over X=0..nt-6, then one peeled even tile X=nt-4)
        int X = 0;
        for (; X + 1 <= nt - 5; X += 2) {
            STEADY_TILE(X,     arA, arB);   // issue->arA, write A(X+1) from arB
            STEADY_TILE(X + 1, arB, arA);
        }
        STEADY_TILE(nt - 4, arA, arB);      // X even: issue A(nt-2)->arA

        { // X = nt-3: issue A(nt-1)->arB (X odd); no stageB
            const int slot_ = (nt - 3) & 3;
            G256_READ_B(slot_);
            G256_READ_A(slot_, 0);
            ISSUE_A(arB, (nt - 1) * BK2);
            G256_MFMA(0);
            __builtin_amdgcn_s_barrier();
            G256_READ_A(slot_, 1);
            asm volatile("s_waitcnt vmcnt(6)" ::: "memory");  // B(nt-2) landed
            WRITE_A((nt - 2) & 3, arA);                       // A(nt-2)
            G256_MFMA(1);
            asm volatile("s_waitcnt lgkmcnt(0)" ::: "memory");
            __builtin_amdgcn_s_barrier();
        }
        { // X = nt-2
            const int slot_ = (nt - 2) & 3;
            G256_READ_B(slot_);
            G256_READ_A(slot_, 0);
            G256_MFMA(0);
            __builtin_amdgcn_s_barrier();
            G256_READ_A(slot_, 1);
            asm volatile("s_waitcnt vmcnt(0)" ::: "memory");  // all landed
            WRITE_A((nt - 1) & 3, arB);                       // A(nt-1)
            G256_MFMA(1);
            asm volatile("s_waitcnt lgkmcnt(0)" ::: "memory");
            __builtin_amdgcn_s_barrier();
        }
        { // X = nt-1
            const int slot_ = (nt - 1) & 3;
            G256_READ_B(slot_);
            G256_READ_A(slot_, 0);
            G256_MFMA(0);
            __builtin_amdgcn_s_barrier();
            G256_READ_A(slot_, 1);
            G256_MFMA(1);
        }
    } else {
        // R4-verified all-DMA schedule
        const ushort* Abase = (const ushort*)args.A[bz] + rowBase * K;
        auto stageA = [&](int slot, int kt) {
            gload_lds16(Abase + sOff0 + (long)kt * BK2, &As[slot][gA0 * 8]);
            gload_lds16(Abase + sOff1 + (long)kt * BK2, &As[slot][gA1 * 8]);
        };

        stageA(0, 0); stageB(0, 0);
        stageA(1, 1); stageB(1, 1);
        stageA(2, 2); stageB(2, 2);
        asm volatile("s_waitcnt vmcnt(8)" ::: "memory");
        __builtin_amdgcn_s_barrier();

        for (int X = 0; X < nt - 3; ++X) {
            const int slot_ = X & 3, st_ = (X + 3) & 3;
            G256_READ_B(slot_);
            G256_READ_A(slot_, 0);
            stageA(st_, X + 3);
            G256_MFMA(0);
            __builtin_amdgcn_s_barrier();
            G256_READ_A(slot_, 1);
            stageB(st_, X + 3);
            G256_MFMA(1);
            asm volatile("s_waitcnt vmcnt(8)" ::: "memory");
            __builtin_amdgcn_s_barrier();
        }
        {
            const int slot_ = (nt - 3) & 3;
            G256_READ_B(slot_);
            G256_READ_A(slot_, 0);
            G256_MFMA(0);
            __builtin_amdgcn_s_barrier();
            G256_READ_A(slot_, 1);
            G256_MFMA(1);
            asm volatile("s_waitcnt vmcnt(4)" ::: "memory");
            __builtin_amdgcn_s_barrier();
        }
        {
            const int slot_ = (nt - 2) & 3;
            G256_READ_B(slot_);
            G256_READ_A(slot_, 0);
            G256_MFMA(0);
            __builtin_amdgcn_s_barrier();
            G256_READ_A(slot_, 1);
            G256_MFMA(1);
            asm volatile("s_waitcnt vmcnt(0)" ::: "memory");
            __builtin_amdgcn_s_barrier();
        }
        {
            const int slot_ = (nt - 1) & 3;
            G256_READ_B(slot_);
            G256_READ_A(slot_, 0);
            G256_MFMA(0);
            __builtin_amdgcn_s_barrier();
            G256_READ_A(slot_, 1);
            G256_MFMA(1);
        }
    }

    // epilogue: C layout col=lane&15, row=(lane>>4)*4+reg
    const int qd = lane >> 4;
    #pragma unroll
    for (int n = 0; n < 4; ++n) {
        const long col = colBase + wn * 64 + n * 16 + fr;
        const float bv = Bi[col];
        #pragma unroll
        for (int m = 0; m < 8; ++m) {
            const long r0 = rowBase + wm * 128 + m * 16 + qd * 4;
            #pragma unroll
            for (int r2 = 0; r2 < 4; ++r2) {
                const float val = acc[m][n][r2] + bv;
                if (BF16OUT)
                    ((ushort*)args.C[bz])[(r0 + r2) * (long)N + col] = f2bf(val);
                else
                    ((float*)args.C[bz])[(r0 + r2) * (long)N + col] = val;
            }
        }
    }
}

// ---------------------------------------------------------------------------
// Fused per-token attention (16x16 head-gram) + LayerNorm (unchanged R5
// structure). One wave per token; 4 tokens per block; zero barriers.
// NOTE: O may alias Qp (in-place over the Q-projection) — per-token reads
// complete (dataflow through MFMA) before the output stores issue.
// ---------------------------------------------------------------------------
#define PMS 40    // fallback Pm row stride (u16)

__global__ __launch_bounds__(256) void attn_ln_mfma(
    const ushort* Qp, const ushort* __restrict__ Kp,
    const ushort* __restrict__ Vp,
    const float* __restrict__ lng, const float* __restrict__ lnb,
    ushort* O)
{
#if HAVE_MFMA_K16
    __shared__ __align__(16) ushort Vs[4][1024];       // per-wave V, swizzled
#else
    __shared__ __align__(16) ushort Vs[4][2048];       // + slack for K32 reads
    __shared__ __align__(16) ushort Pm[4][16 * PMS];
#endif
    __shared__ __align__(16) float Os[4][16 * 68];     // per-wave out transpose

    const int tid  = threadIdx.x;
    const int w    = tid >> 6;
    const int lane = tid & 63;
    const long tok  = (long)blockIdx.x * 4 + w;
    const long base = tok * DMODEL;

    // stage V: linear LDS dest, pre-swizzled global source.
    {
        const int i0 = lane, i1 = lane + 64;
        const int g0 = i0 >> 3, d80 = (i0 & 7) ^ (((i0 >> 5) & 3) << 1);
        const int g1 = i1 >> 3, d81 = (i1 & 7) ^ (((i1 >> 5) & 3) << 1);
        gload_lds16(Vp + base + g0 * 64 + d80 * 8, &Vs[w][i0 * 8]);
        gload_lds16(Vp + base + g1 * 64 + d81 * 8, &Vs[w][i1 * 8]);
    }

    const int fr = lane & 15;
    const int hi = lane >> 4;
    const int fs = hi * 8;

    // QK^T fragments directly from global (token row is 2KB, cache-resident)
    const bf16x8 aq0 = *(const bf16x8*)(Qp + base + fr * 64 + fs);
    const bf16x8 aq1 = *(const bf16x8*)(Qp + base + fr * 64 + fs + 32);
    const bf16x8 bk0 = *(const bf16x8*)(Kp + base + fr * 64 + fs);
    const bf16x8 bk1 = *(const bf16x8*)(Kp + base + fr * 64 + fs + 32);

    // swapped operands: E^T[g][h]; lane (fr,hi) holds E[h=fr][g=hi*4+r]
    f32x4 e = (f32x4){0.f, 0.f, 0.f, 0.f};
    e = mfma16(bk0, aq0, e);
    e = mfma16(bk1, aq1, e);

    // softmax over g: 4-local + shfl_xor(16,32)
    float x[4];
    #pragma unroll
    for (int r = 0; r < 4; ++r) x[r] = e[r] * 0.03125f;   // 1/sqrt(1024)
    float mx = fmaxf(fmaxf(x[0], x[1]), fmaxf(x[2], x[3]));
    mx = fmaxf(mx, __shfl_xor(mx, 16, 64));
    mx = fmaxf(mx, __shfl_xor(mx, 32, 64));
    float ex[4], sm;
    #pragma unroll
    for (int r = 0; r < 4; ++r) ex[r] = __expf(x[r] - mx);
    sm = (ex[0] + ex[1]) + (ex[2] + ex[3]);
    sm += __shfl_xor(sm, 16, 64);
    sm += __shfl_xor(sm, 32, 64);
    const float inv = 1.0f / sm;
    float p[4];
    #pragma unroll
    for (int r = 0; r < 4; ++r) p[r] = ex[r] * inv;

    f32x4 o[4];

#if HAVE_MFMA_K16
    // P is already the 16x16x16 A-fragment: A[h=fr][k=g=hi*4+j] = p[j]
    s16x4 pa;
    #pragma unroll
    for (int r = 0; r < 4; ++r) pa[r] = (short)f2bf(p[r]);

    asm volatile("s_waitcnt vmcnt(0)" ::: "memory");   // V staged (wave-local)

    #pragma unroll
    for (int dblk = 0; dblk < 4; ++dblk) {
        s16x4 bv;
        #pragma unroll
        for (int j = 0; j < 4; ++j) {
            const int g = hi * 4 + j;
            const int d = dblk * 16 + fr;
            const int ad = g * 64 + (((d >> 3) ^ (((g >> 2) & 3) << 1)) * 8) + (d & 7);
            bv[j] = (short)Vs[w][ad];
        }
        o[dblk] = __builtin_amdgcn_mfma_f32_16x16x16bf16_1k(
            pa, bv, (f32x4){0.f, 0.f, 0.f, 0.f}, 0, 0, 0);
    }
#else
    // fallback: bounce P through LDS, K=32 MFMA with zero-padded k>=16
    *(u16x4*)&Pm[w][fr * PMS + 16 + hi * 4] = (u16x4){0, 0, 0, 0};
    #pragma unroll
    for (int r = 0; r < 4; ++r)
        Pm[w][fr * PMS + hi * 4 + r] = f2bf(p[r]);
    asm volatile("s_waitcnt vmcnt(0)" ::: "memory");
    const bf16x8 pa8 = *(const bf16x8*)&Pm[w][fr * PMS + fs];
    #pragma unroll
    for (int dblk = 0; dblk < 4; ++dblk) {
        BU bu;
        #pragma unroll
        for (int j = 0; j < 8; ++j) {
            const int g = fs + j;                     // g>=16: garbage * P=0
            const int d = dblk * 16 + fr;
            const int ad = g * 64 + (((d >> 3) ^ (((g >> 2) & 3) << 1)) * 8) + (d & 7);
            bu.u[j] = Vs[w][ad];
        }
        o[dblk] = mfma16(pa8, bu.b, (f32x4){0.f, 0.f, 0.f, 0.f});
    }
#endif
    // lane holds out[h=hi*4+r][d=dblk*16+fr]

    // LayerNorm stats over 1024: 16 regs/lane x 64 lanes
    float s1 = 0.f, s2 = 0.f;
    #pragma unroll
    for (int dblk = 0; dblk < 4; ++dblk)
        #pragma unroll
        for (int r = 0; r < 4; ++r) { const float v = o[dblk][r]; s1 += v; s2 += v * v; }
    #pragma unroll
    for (int m = 1; m < 64; m <<= 1) {
        s1 += __shfl_xor(s1, m, 64);
        s2 += __shfl_xor(s2, m, 64);
    }
    const float mu   = s1 * (1.f / DMODEL);
    const float var  = s2 * (1.f / DMODEL) - mu * mu;
    const float rstd = rsqrtf(var + 1e-5f);

    // transpose via per-wave LDS (stride 68: conflict-free both directions)
    #pragma unroll
    for (int dblk = 0; dblk < 4; ++dblk)
        #pragma unroll
        for (int r = 0; r < 4; ++r)
            Os[w][(hi * 4 + r) * 68 + dblk * 16 + fr] = (o[dblk][r] - mu) * rstd;

    // lane owns token elems lane*16 .. lane*16+15
    u16x8 s0, s1v;
    #pragma unroll
    for (int c = 0; c < 4; ++c) {
        const f32x4 yv = *(const f32x4*)&Os[w][(lane >> 2) * 68 + (lane & 3) * 16 + c * 4];
        const f32x4 lg = *(const f32x4*)(lng + lane * 16 + c * 4);
        const f32x4 lb = *(const f32x4*)(lnb + lane * 16 + c * 4);
        #pragma unroll
        for (int j = 0; j < 4; ++j) {
            const ushort hv = f2bf(yv[j] * lg[j] + lb[j]);
            if (c < 2) s0[c * 4 + j] = hv; else s1v[(c - 2) * 4 + j] = hv;
        }
    }
    *(u16x8*)(O + base + lane * 16)     = s0;
    *(u16x8*)(O + base + lane * 16 + 8) = s1v;
}

// ---------------------------------------------------------------------------
// launch — chunked pipeline. Input cvt ELIMINATED: gemm1 reads fp32 q/k/v
// directly (reg-staged A). ws: [4x bf16 weights | qp, vp bf16 per chunk].
// kp (bf16 K-proj) borrows the d_out chunk; attention writes bf16 output
// IN-PLACE over qp; gemm2 reads qp.
// ---------------------------------------------------------------------------
extern "C" void kernel_launch(void* const* d_in, const int* in_sizes, int n_in,
                              void* d_out, int out_size, void* d_ws, size_t ws_size,
                              hipStream_t stream)
{
    const float* query = (const float*)d_in[0];
    const float* key   = (const float*)d_in[1];
    const float* value = (const float*)d_in[2];
    const float* Wq = (const float*)d_in[3];
    const float* bq = (const float*)d_in[4];
    const float* Wk = (const float*)d_in[5];
    const float* bk = (const float*)d_in[6];
    const float* Wv = (const float*)d_in[7];
    const float* bv = (const float*)d_in[8];
    const float* lng = (const float*)d_in[9];
    const float* lnb = (const float*)d_in[10];
    const float* Wo = (const float*)d_in[11];
    const float* bo = (const float*)d_in[12];
    float* out = (float*)d_out;

    const long WELEMS = (long)DMODEL * DMODEL;       // 1Mi elems per weight

    ushort* wq_b = (ushort*)d_ws;
    ushort* wk_b = wq_b + WELEMS;
    ushort* wv_b = wk_b + WELEMS;
    ushort* wo_b = wv_b + WELEMS;
    ushort* cbuf = wo_b + WELEMS;                    // per-chunk region

    // bytes needed: 8MB weights + CM*1024*(2 bf16 bufs * 2B) = 8MB + CM*4096
    // NC capped at 64 so CM stays a multiple of 256 (BM2 tile).
    int NC = 1;
    while (NC < 64 &&
           (size_t)(8 * WELEMS) + (size_t)(TOKENS / NC) * DMODEL * 4 > ws_size)
        NC <<= 1;
    const int CM = TOKENS / NC;                 // tokens per chunk (mult of 256)
    const size_t CE = (size_t)CM * DMODEL;      // elems per chunk buffer

    ushort* qp = cbuf;            // bf16 Q-projection; attn output in-place
    ushort* vp = qp + CE;         // bf16 V-projection

    // 0) convert weights fp32 -> bf16 (once)
    {
        CvtArgs cw;
        cw.src[0] = Wq; cw.src[1] = Wk; cw.src[2] = Wv; cw.src[3] = Wo;
        cw.dst[0] = wq_b; cw.dst[1] = wk_b; cw.dst[2] = wv_b; cw.dst[3] = wo_b;
        cvt_f32_bf16<<<dim3((unsigned)(WELEMS / 2048), 4), 256, 0, stream>>>(cw);
    }

    for (int c = 0; c < NC; ++c) {
        const size_t off = (size_t)c * CE;
        ushort* kp = (ushort*)(out + off);      // bf16 scratch in d_out chunk

        // 1) fused QKV projections from fp32 inputs, bf16 outputs
        GemmArgs g1;
        g1.A[0] = query + off; g1.A[1] = key + off; g1.A[2] = value + off;
        g1.W[0] = wq_b;  g1.W[1] = wk_b; g1.W[2] = wv_b;
        g1.Bi[0] = bq;   g1.Bi[1] = bk;  g1.Bi[2] = bv;
        g1.C[0] = qp;    g1.C[1] = kp;   g1.C[2] = vp;
        gemm256<1, 1><<<dim3(DMODEL / BN2, CM / BM2, 3), 512, 0, stream>>>(
            g1, DMODEL, DMODEL);

        // 2) per-token attention + LayerNorm -> bf16 in-place over qp
        attn_ln_mfma<<<CM / 4, 256, 0, stream>>>(qp, kp, vp, lng, lnb, qp);

        // 3) output projection -> d_out chunk fp32 (overwrites kp scratch)
        GemmArgs g2;
        g2.A[0] = g2.A[1] = g2.A[2] = qp;
        g2.W[0] = g2.W[1] = g2.W[2] = wo_b;
        g2.Bi[0] = g2.Bi[1] = g2.Bi[2] = bo;
        g2.C[0] = g2.C[1] = g2.C[2] = out + off;
        gemm256<0, 0><<<dim3(DMODEL / BN2, CM / BM2, 1), 512, 0, stream>>>(
            g2, DMODEL, DMODEL);
    }
}